// Round 1
// 718.038 us; speedup vs baseline: 1.2547x; 1.2547x over previous
//
#include <hip/hip_runtime.h>
#include <hip/hip_bf16.h>

#define NB 1024
#define DM 1024
#define DH 64
#define NH 16
#define NA 4
#define FEPS 1e-6f

// ---------------- K1: routing (logits, softmax, top-4, head lists) ----------------
__global__ __launch_bounds__(256) void k_route(
    const float* __restrict__ query,
    const float* __restrict__ We,
    const float* __restrict__ be,
    int* __restrict__ cnt,
    int* __restrict__ topi,
    float* __restrict__ topp,
    float* __restrict__ topl,
    int* __restrict__ slot,
    int* __restrict__ rows)
{
    int b = blockIdx.x, t = threadIdx.x;
    __shared__ float qs[DM];
    __shared__ float lg[NH];
    __shared__ int   sti[NA];
    __shared__ float stp[NA], stl[NA];
    ((float4*)qs)[t] = ((const float4*)(query + (size_t)b*DM))[t];
    __syncthreads();
    // 16 heads x 16 threads each
    int h = t >> 4, l = t & 15;
    const float* w = We + h*DM;
    float p = 0.f;
    for (int j = l; j < DM; j += 16) p += qs[j]*w[j];
    #pragma unroll
    for (int d = 8; d > 0; d >>= 1) p += __shfl_down(p, d, 16);
    if (l == 0) lg[h] = p + be[h];
    __syncthreads();
    if (t == 0) {
        float mx = lg[0];
        for (int i = 1; i < NH; i++) mx = fmaxf(mx, lg[i]);
        float s = 0.f, e[NH];
        for (int i = 0; i < NH; i++) { e[i] = expf(lg[i]-mx); s += e[i]; }
        float inv = 1.f/s;
        unsigned used = 0;
        for (int a = 0; a < NA; a++) {
            int bi = -1; float bv = -1e30f;
            for (int i = 0; i < NH; i++)
                if (!((used>>i)&1u) && lg[i] > bv) { bv = lg[i]; bi = i; }
            used |= 1u << bi;
            sti[a] = bi; stp[a] = e[bi]*inv; stl[a] = lg[bi];
        }
    }
    __syncthreads();
    if (t < NA) {
        int hh = sti[t];
        topi[b*NA+t] = hh; topp[b*NA+t] = stp[t]; topl[b*NA+t] = stl[t];
        int pos = atomicAdd(&cnt[hh], 1);
        rows[hh*NB + pos] = b*NA + t;   // code = b*4 + slot
    }
    if (t < NH) {
        int sl = -1;
        #pragma unroll
        for (int a = 0; a < NA; a++) if (sti[a] == t) sl = a;
        slot[b*NH + t] = sl;
    }
}

// ---------------- K2: gathered per-head projection GEMM (64 rows x 64 dims) -------
__global__ __launch_bounds__(256) void k_proj(
    const float* __restrict__ Xq, const float* __restrict__ Xk, const float* __restrict__ Xv,
    const float* __restrict__ Wq, const float* __restrict__ Wk, const float* __restrict__ Wv,
    const float* __restrict__ bq, const float* __restrict__ bk, const float* __restrict__ bv,
    const int* __restrict__ cnt, const int* __restrict__ rows,
    float* __restrict__ qb, float* __restrict__ kb, float* __restrict__ vb)
{
    int h = blockIdx.x, c = blockIdx.y, pz = blockIdx.z;
    int n = cnt[h];
    int r0 = c*64;
    if (r0 >= n) return;
    int nr = min(64, n - r0);
    const float* X    = pz==0 ? Xq : (pz==1 ? Xk : Xv);
    const float* W    = (pz==0 ? Wq : (pz==1 ? Wk : Wv)) + (size_t)h*DH*DM;
    const float* bias = (pz==0 ? bq : (pz==1 ? bk : bv)) + h*DH;
    float* outp = pz==0 ? qb : (pz==1 ? kb : vb);

    __shared__ float As[64*65];   // +1 pad breaks bank conflicts
    __shared__ float Bs[64*65];
    __shared__ int codes[64];
    int t = threadIdx.x;
    if (t < 64) codes[t] = rows[h*NB + r0 + min(t, nr-1)];
    __syncthreads();
    int tx = t & 15, ty = t >> 4;
    float acc[4][4] = {};
    int lr = t >> 2, k0 = (t & 3)*16;
    for (int kt = 0; kt < DM; kt += 64) {
        const float* srcA = X + (size_t)(codes[lr] >> 2)*DM + kt + k0;
        float* dA = As + lr*65 + k0;
        const float* srcB = W + (size_t)lr*DM + kt + k0;
        float* dB = Bs + lr*65 + k0;
        #pragma unroll
        for (int j = 0; j < 4; j++) {
            float4 fa = ((const float4*)srcA)[j];
            dA[j*4+0]=fa.x; dA[j*4+1]=fa.y; dA[j*4+2]=fa.z; dA[j*4+3]=fa.w;
            float4 fb = ((const float4*)srcB)[j];
            dB[j*4+0]=fb.x; dB[j*4+1]=fb.y; dB[j*4+2]=fb.z; dB[j*4+3]=fb.w;
        }
        __syncthreads();
        #pragma unroll 4
        for (int k = 0; k < 64; k++) {
            float a0[4], b0[4];
            #pragma unroll
            for (int i=0;i<4;i++) a0[i] = As[(ty*4+i)*65 + k];
            #pragma unroll
            for (int j=0;j<4;j++) b0[j] = Bs[(tx*4+j)*65 + k];
            #pragma unroll
            for (int i=0;i<4;i++)
                #pragma unroll
                for (int j=0;j<4;j++) acc[i][j] += a0[i]*b0[j];
        }
        __syncthreads();
    }
    #pragma unroll
    for (int i = 0; i < 4; i++) {
        int r = ty*4+i;
        if (r < nr) {
            int code = codes[r];
            #pragma unroll
            for (int j = 0; j < 4; j++)
                outp[code*DH + tx*4+j] = acc[i][j] + bias[tx*4+j];
        }
    }
}

// ---------------- K3: per-(b,h) state copy or linear-attention update -------------
__global__ __launch_bounds__(256) void k_update(
    const float* __restrict__ matrix,
    const float* __restrict__ normalizer,
    const float* __restrict__ Ww, const float* __restrict__ bw,
    const float* __restrict__ dlog,
    const int* __restrict__ slot, const float* __restrict__ topl,
    const float* __restrict__ qb, const float* __restrict__ kb,
    const float* __restrict__ vb, float* __restrict__ ob,
    float* __restrict__ om, float* __restrict__ on)
{
    int bh = blockIdx.x, t = threadIdx.x;
    const float* S = matrix + (size_t)bh*(DH*DH);
    float* So = om + (size_t)bh*(DH*DH);
    int sl = slot[bh];
    if (sl < 0) {
        // pure copy path (12/16 of all blocks): f32 -> f32
        #pragma unroll
        for (int j = 0; j < 4; j++) {
            int i4 = t + 256*j;
            ((float4*)So)[i4] = ((const float4*)S)[i4];
        }
        if (t < DH)
            on[(size_t)bh*DH + t] = normalizer[(size_t)bh*DH + t];
        return;
    }
    int b = bh >> 4, h = bh & 15;
    int code = b*NA + sl;
    __shared__ float st[DH*DH];
    __shared__ float pq[DH], pk[DH], vv[DH], qv[DH], Zs[DH];
    __shared__ float part[256];
    __shared__ float fd[DH], gd[DH];
    __shared__ float scal[4];
    if (t < DH) {
        float qq = qb[code*DH + t]; qv[t] = qq;
        float kk = kb[code*DH + t];
        pq[t] = qq > 0.f ? qq + 1.f : expf(qq);   // elu+1
        pk[t] = kk > 0.f ? kk + 1.f : expf(kk);
        vv[t] = vb[code*DH + t];
        Zs[t] = normalizer[(size_t)bh*DH + t];
    }
    #pragma unroll
    for (int j = 0; j < 4; j++)
        ((float4*)st)[t + 256*j] = ((const float4*)S)[t + 256*j];
    __syncthreads();
    // partial column sums of phi_q^T S : 4 d-groups x 64 columns
    {
        int e = t & 63, dg = t >> 6;
        float s = 0.f;
        #pragma unroll
        for (int d = 0; d < 16; d++) s += pq[dg*16 + d] * st[(dg*16+d)*DH + e];
        part[t] = s;
    }
    if (t < 64) {   // wave 0: scalar reductions
        float r1 = pq[t]*pk[t];            // phi_q . phi_k
        float r2 = pq[t]*(Zs[t]+pk[t]);    // phi_q . Z_new
        #pragma unroll
        for (int d = 32; d > 0; d >>= 1) {
            r1 += __shfl_down(r1, d, 64);
            r2 += __shfl_down(r2, d, 64);
        }
        if (t == 0) { scal[0] = r1; scal[1] = r2 + FEPS; }
    }
    __syncthreads();
    float pqk = scal[0], den = scal[1];
    if (t < 64) {
        float cs = part[t] + part[64+t] + part[128+t] + part[192+t];
        float o = (cs + pqk*vv[t]) / den;
        ob[code*DH + t] = o;
        float r3 = (o + qv[t]) * Ww[h*DH + t];
        #pragma unroll
        for (int d = 32; d > 0; d >>= 1) r3 += __shfl_down(r3, d, 64);
        if (t == 0) {
            float wl = topl[code] + r3 + bw[h];
            scal[2] = 1.f/(1.f + expf(-wl));   // wp
        }
    }
    __syncthreads();
    float wp = scal[2];
    if (t < 64) {
        float dec = 1.f/(1.f + expf(-dlog[h*DH + t]));
        float f1 = 1.f - wp*dec;
        fd[t] = f1;
        gd[t] = wp*pk[t];
        on[(size_t)bh*DH + t] = Zs[t]*f1 + wp*pk[t];
    }
    __syncthreads();
    #pragma unroll
    for (int j = 0; j < 4; j++) {
        int i4 = t + 256*j;
        int d = i4 >> 4, e0 = (i4 & 15)*4;   // 16 float4 per 64-wide row
        float4 f = ((const float4*)st)[i4];
        float F = fd[d], G = gd[d];
        float4 u = { f.x*F + G*vv[e0],   f.y*F + G*vv[e0+1],
                     f.z*F + G*vv[e0+2], f.w*F + G*vv[e0+3] };
        ((float4*)So)[i4] = u;
    }
}

// ---------------- K4a: init merged with bias term: sum_a top_p[a]*bo[h_a][m] -----
__global__ __launch_bounds__(256) void k_bias(
    const int* __restrict__ topi, const float* __restrict__ topp,
    const float* __restrict__ bo, float* __restrict__ merged)
{
    int b = blockIdx.x, t = threadIdx.x;
    __shared__ float tp[NA];
    __shared__ int   hh[NA];
    if (t < NA) { tp[t] = topp[b*NA+t]; hh[t] = topi[b*NA+t]; }
    __syncthreads();
    float ax = 0.f, ay = 0.f, az = 0.f, aw = 0.f;
    #pragma unroll
    for (int a = 0; a < NA; a++) {
        float4 w = ((const float4*)(bo + (size_t)hh[a]*DM))[t];
        float p = tp[a];
        ax += p*w.x; ay += p*w.y; az += p*w.z; aw += p*w.w;
    }
    float4 u = { ax, ay, az, aw };
    ((float4*)merged)[(size_t)b*(DM/4) + t] = u;
}

// ---------------- K4b: head-grouped output-projection GEMM -----------------------
// Per block: (head h, 64-row tile of h's gathered rows, 64-wide m tile).
// A = top_p-scaled ob rows (64x64), B = contiguous Wo[h] slab (64 m x 64 e).
// C-tile atomically added into merged (each row b gets exactly NA=4 contributions).
__global__ __launch_bounds__(256) void k_mergemm(
    const float* __restrict__ Wo,
    const int* __restrict__ cnt, const int* __restrict__ rows,
    const float* __restrict__ topp, const float* __restrict__ ob,
    float* __restrict__ merged)
{
    int h = blockIdx.x, rt = blockIdx.y, mt = blockIdx.z;
    int n = cnt[h];
    int r0 = rt*64;
    if (r0 >= n) return;
    int nr = min(64, n - r0);

    __shared__ float As[64*65];
    __shared__ float Bs[64*65];
    __shared__ int   codes[64];
    __shared__ float scl[64];
    int t = threadIdx.x;
    if (t < 64) {
        int c = rows[h*NB + r0 + min(t, nr-1)];
        codes[t] = c;
        scl[t] = topp[c];
    }
    __syncthreads();

    int lr = t >> 2, e0 = (t & 3)*16;
    {
        const float* srcA = ob + (size_t)codes[lr]*DH + e0;
        float sc = scl[lr];
        float* dA = As + lr*65 + e0;
        const float* srcB = Wo + (size_t)h*DM*DH + (size_t)(mt*64 + lr)*DH + e0;
        float* dB = Bs + lr*65 + e0;
        #pragma unroll
        for (int j = 0; j < 4; j++) {
            float4 fa = ((const float4*)srcA)[j];
            dA[j*4+0]=fa.x*sc; dA[j*4+1]=fa.y*sc; dA[j*4+2]=fa.z*sc; dA[j*4+3]=fa.w*sc;
            float4 fb = ((const float4*)srcB)[j];
            dB[j*4+0]=fb.x; dB[j*4+1]=fb.y; dB[j*4+2]=fb.z; dB[j*4+3]=fb.w;
        }
    }
    __syncthreads();

    int tx = t & 15, ty = t >> 4;
    float acc[4][4] = {};
    #pragma unroll 4
    for (int k = 0; k < 64; k++) {
        float a0[4], b0[4];
        #pragma unroll
        for (int i=0;i<4;i++) a0[i] = As[(ty*4+i)*65 + k];
        #pragma unroll
        for (int j=0;j<4;j++) b0[j] = Bs[(tx*4+j)*65 + k];
        #pragma unroll
        for (int i=0;i<4;i++)
            #pragma unroll
            for (int j=0;j<4;j++) acc[i][j] += a0[i]*b0[j];
    }

    int mbase = mt*64 + tx*4;
    #pragma unroll
    for (int i = 0; i < 4; i++) {
        int r = ty*4 + i;
        if (r < nr) {
            int b = codes[r] >> 2;
            float* dst = merged + (size_t)b*DM + mbase;
            #pragma unroll
            for (int j = 0; j < 4; j++)
                atomicAdd(&dst[j], acc[i][j]);
        }
    }
}

extern "C" void kernel_launch(void* const* d_in, const int* in_sizes, int n_in,
                              void* d_out, int out_size, void* d_ws, size_t ws_size,
                              hipStream_t stream)
{
    const float* query  = (const float*)d_in[0];
    const float* key    = (const float*)d_in[1];
    const float* value  = (const float*)d_in[2];
    const float* matrix = (const float*)d_in[3];
    const float* normal = (const float*)d_in[4];
    const float* Wq = (const float*)d_in[5];
    const float* bq = (const float*)d_in[6];
    const float* Wk = (const float*)d_in[7];
    const float* bk = (const float*)d_in[8];
    const float* Wv = (const float*)d_in[9];
    const float* bv = (const float*)d_in[10];
    const float* Wo = (const float*)d_in[11];
    const float* bo = (const float*)d_in[12];
    const float* We = (const float*)d_in[13];
    const float* be = (const float*)d_in[14];
    const float* Ww = (const float*)d_in[15];
    const float* bw = (const float*)d_in[16];
    const float* dlog = (const float*)d_in[17];

    float* ws = (float*)d_ws;
    int*   cnt  = (int*)ws;                  // 16 ints
    int*   topi = (int*)(ws + 16);           // 4096
    float* topp = ws + 16 + 4096;            // 4096
    float* topl = topp + 4096;               // 4096
    int*   slot = (int*)(topl + 4096);       // 16384
    int*   rows = slot + 16384;              // 16384
    float* qb = (float*)(rows + 16384);      // 262144
    float* kb = qb + 262144;
    float* vb = kb + 262144;
    float* ob = vb + 262144;

    float* out_merged = (float*)d_out;
    float* out_matrix = out_merged + (size_t)NB*DM;
    float* out_norm   = out_matrix + (size_t)NB*NH*DH*DH;

    hipMemsetAsync(cnt, 0, 16*sizeof(int), stream);
    k_route<<<NB, 256, 0, stream>>>(query, We, be, cnt, topi, topp, topl, slot, rows);
    k_bias<<<NB, 256, 0, stream>>>(topi, topp, bo, out_merged);
    k_proj<<<dim3(NH, NB/64, 3), 256, 0, stream>>>(query, key, value, Wq, Wk, Wv,
                                                   bq, bk, bv, cnt, rows, qb, kb, vb);
    k_update<<<NB*NH, 256, 0, stream>>>(matrix, normal, Ww, bw, dlog, slot, topl,
                                        qb, kb, vb, ob, out_matrix, out_norm);
    k_mergemm<<<dim3(NH, NB/64, DM/64), 256, 0, stream>>>(Wo, cnt, rows, topp, ob,
                                                          out_merged);
}

// Round 2
// 628.792 us; speedup vs baseline: 1.4328x; 1.1419x over previous
//
#include <hip/hip_runtime.h>
#include <hip/hip_bf16.h>

#define NB 1024
#define DM 1024
#define DH 64
#define NH 16
#define NA 4
#define FEPS 1e-6f
#define LP 68   // k-major LDS pad: multiple of 4 (16B alignment), 68%32=4 spreads banks

// ---------------- K1: routing (logits, softmax, top-4, head lists) ----------------
__global__ __launch_bounds__(256) void k_route(
    const float* __restrict__ query,
    const float* __restrict__ We,
    const float* __restrict__ be,
    int* __restrict__ cnt,
    int* __restrict__ topi,
    float* __restrict__ topp,
    float* __restrict__ topl,
    int* __restrict__ slot,
    int* __restrict__ rows)
{
    int b = blockIdx.x, t = threadIdx.x;
    __shared__ float qs[DM];
    __shared__ float lg[NH];
    __shared__ int   sti[NA];
    __shared__ float stp[NA], stl[NA];
    ((float4*)qs)[t] = ((const float4*)(query + (size_t)b*DM))[t];
    __syncthreads();
    // 16 heads x 16 threads each
    int h = t >> 4, l = t & 15;
    const float* w = We + h*DM;
    float p = 0.f;
    for (int j = l; j < DM; j += 16) p += qs[j]*w[j];
    #pragma unroll
    for (int d = 8; d > 0; d >>= 1) p += __shfl_down(p, d, 16);
    if (l == 0) lg[h] = p + be[h];
    __syncthreads();
    if (t == 0) {
        float mx = lg[0];
        for (int i = 1; i < NH; i++) mx = fmaxf(mx, lg[i]);
        float s = 0.f, e[NH];
        for (int i = 0; i < NH; i++) { e[i] = expf(lg[i]-mx); s += e[i]; }
        float inv = 1.f/s;
        unsigned used = 0;
        for (int a = 0; a < NA; a++) {
            int bi = -1; float bv = -1e30f;
            for (int i = 0; i < NH; i++)
                if (!((used>>i)&1u) && lg[i] > bv) { bv = lg[i]; bi = i; }
            used |= 1u << bi;
            sti[a] = bi; stp[a] = e[bi]*inv; stl[a] = lg[bi];
        }
    }
    __syncthreads();
    if (t < NA) {
        int hh = sti[t];
        topi[b*NA+t] = hh; topp[b*NA+t] = stp[t]; topl[b*NA+t] = stl[t];
        int pos = atomicAdd(&cnt[hh], 1);
        rows[hh*NB + pos] = b*NA + t;   // code = b*4 + slot
    }
    if (t < NH) {
        int sl = -1;
        #pragma unroll
        for (int a = 0; a < NA; a++) if (sti[a] == t) sl = a;
        slot[b*NH + t] = sl;
    }
}

// ---------------- K2: gathered per-head projection GEMM (64 rows x 64 dims) -------
// LDS tiles stored K-MAJOR (As[k][r], Bs[k][m]) so the inner loop is exactly
// 2x ds_read_b128 per k-step (A-frag is a 16-lane broadcast; B-frag 2-way=free).
__global__ __launch_bounds__(256) void k_proj(
    const float* __restrict__ Xq, const float* __restrict__ Xk, const float* __restrict__ Xv,
    const float* __restrict__ Wq, const float* __restrict__ Wk, const float* __restrict__ Wv,
    const float* __restrict__ bq, const float* __restrict__ bk, const float* __restrict__ bv,
    const int* __restrict__ cnt, const int* __restrict__ rows,
    float* __restrict__ qb, float* __restrict__ kb, float* __restrict__ vb)
{
    int h = blockIdx.x, c = blockIdx.y, pz = blockIdx.z;
    int n = cnt[h];
    int r0 = c*64;
    if (r0 >= n) return;
    int nr = min(64, n - r0);
    const float* X    = pz==0 ? Xq : (pz==1 ? Xk : Xv);
    const float* W    = (pz==0 ? Wq : (pz==1 ? Wk : Wv)) + (size_t)h*DH*DM;
    const float* bias = (pz==0 ? bq : (pz==1 ? bk : bv)) + h*DH;
    float* outp = pz==0 ? qb : (pz==1 ? kb : vb);

    __shared__ float As[64*LP];   // k-major: As[k*LP + r]
    __shared__ float Bs[64*LP];   // k-major: Bs[k*LP + m]
    __shared__ int codes[64];
    int t = threadIdx.x;
    if (t < 64) codes[t] = rows[h*NB + r0 + min(t, nr-1)];
    __syncthreads();
    int tx = t & 15, ty = t >> 4;
    float acc[4][4] = {};
    int lr = t >> 2, k0 = (t & 3)*16;
    const float* srcA0 = X + (size_t)(codes[lr] >> 2)*DM + k0;
    const float* srcB0 = W + (size_t)lr*DM + k0;
    for (int kt = 0; kt < DM; kt += 64) {
        #pragma unroll
        for (int j = 0; j < 4; j++) {
            float4 fa = ((const float4*)(srcA0 + kt))[j];
            float4 fb = ((const float4*)(srcB0 + kt))[j];
            int kk = k0 + j*4;
            As[(kk+0)*LP + lr] = fa.x; As[(kk+1)*LP + lr] = fa.y;
            As[(kk+2)*LP + lr] = fa.z; As[(kk+3)*LP + lr] = fa.w;
            Bs[(kk+0)*LP + lr] = fb.x; Bs[(kk+1)*LP + lr] = fb.y;
            Bs[(kk+2)*LP + lr] = fb.z; Bs[(kk+3)*LP + lr] = fb.w;
        }
        __syncthreads();
        #pragma unroll 8
        for (int k = 0; k < 64; k++) {
            float4 a4 = *(const float4*)(As + k*LP + ty*4);
            float4 b4 = *(const float4*)(Bs + k*LP + tx*4);
            float a0[4] = {a4.x, a4.y, a4.z, a4.w};
            float b0[4] = {b4.x, b4.y, b4.z, b4.w};
            #pragma unroll
            for (int i=0;i<4;i++)
                #pragma unroll
                for (int j=0;j<4;j++) acc[i][j] += a0[i]*b0[j];
        }
        __syncthreads();
    }
    #pragma unroll
    for (int i = 0; i < 4; i++) {
        int r = ty*4+i;
        if (r < nr) {
            int code = codes[r];
            #pragma unroll
            for (int j = 0; j < 4; j++)
                outp[code*DH + tx*4+j] = acc[i][j] + bias[tx*4+j];
        }
    }
}

// ---------------- K3: per-(b,h) state copy or linear-attention update -------------
__global__ __launch_bounds__(256) void k_update(
    const float* __restrict__ matrix,
    const float* __restrict__ normalizer,
    const float* __restrict__ Ww, const float* __restrict__ bw,
    const float* __restrict__ dlog,
    const int* __restrict__ slot, const float* __restrict__ topl,
    const float* __restrict__ qb, const float* __restrict__ kb,
    const float* __restrict__ vb, float* __restrict__ ob,
    float* __restrict__ om, float* __restrict__ on)
{
    int bh = blockIdx.x, t = threadIdx.x;
    const float* S = matrix + (size_t)bh*(DH*DH);
    float* So = om + (size_t)bh*(DH*DH);
    int sl = slot[bh];
    if (sl < 0) {
        // pure copy path (12/16 of all blocks): f32 -> f32
        #pragma unroll
        for (int j = 0; j < 4; j++) {
            int i4 = t + 256*j;
            ((float4*)So)[i4] = ((const float4*)S)[i4];
        }
        if (t < DH)
            on[(size_t)bh*DH + t] = normalizer[(size_t)bh*DH + t];
        return;
    }
    int b = bh >> 4, h = bh & 15;
    int code = b*NA + sl;
    __shared__ float st[DH*DH];
    __shared__ float pq[DH], pk[DH], vv[DH], qv[DH], Zs[DH];
    __shared__ float part[256];
    __shared__ float fd[DH], gd[DH];
    __shared__ float scal[4];
    if (t < DH) {
        float qq = qb[code*DH + t]; qv[t] = qq;
        float kk = kb[code*DH + t];
        pq[t] = qq > 0.f ? qq + 1.f : expf(qq);   // elu+1
        pk[t] = kk > 0.f ? kk + 1.f : expf(kk);
        vv[t] = vb[code*DH + t];
        Zs[t] = normalizer[(size_t)bh*DH + t];
    }
    #pragma unroll
    for (int j = 0; j < 4; j++)
        ((float4*)st)[t + 256*j] = ((const float4*)S)[t + 256*j];
    __syncthreads();
    // partial column sums of phi_q^T S : 4 d-groups x 64 columns
    {
        int e = t & 63, dg = t >> 6;
        float s = 0.f;
        #pragma unroll
        for (int d = 0; d < 16; d++) s += pq[dg*16 + d] * st[(dg*16+d)*DH + e];
        part[t] = s;
    }
    if (t < 64) {   // wave 0: scalar reductions
        float r1 = pq[t]*pk[t];            // phi_q . phi_k
        float r2 = pq[t]*(Zs[t]+pk[t]);    // phi_q . Z_new
        #pragma unroll
        for (int d = 32; d > 0; d >>= 1) {
            r1 += __shfl_down(r1, d, 64);
            r2 += __shfl_down(r2, d, 64);
        }
        if (t == 0) { scal[0] = r1; scal[1] = r2 + FEPS; }
    }
    __syncthreads();
    float pqk = scal[0], den = scal[1];
    if (t < 64) {
        float cs = part[t] + part[64+t] + part[128+t] + part[192+t];
        float o = (cs + pqk*vv[t]) / den;
        ob[code*DH + t] = o;
        float r3 = (o + qv[t]) * Ww[h*DH + t];
        #pragma unroll
        for (int d = 32; d > 0; d >>= 1) r3 += __shfl_down(r3, d, 64);
        if (t == 0) {
            float wl = topl[code] + r3 + bw[h];
            scal[2] = 1.f/(1.f + expf(-wl));   // wp
        }
    }
    __syncthreads();
    float wp = scal[2];
    if (t < 64) {
        float dec = 1.f/(1.f + expf(-dlog[h*DH + t]));
        float f1 = 1.f - wp*dec;
        fd[t] = f1;
        gd[t] = wp*pk[t];
        on[(size_t)bh*DH + t] = Zs[t]*f1 + wp*pk[t];
    }
    __syncthreads();
    #pragma unroll
    for (int j = 0; j < 4; j++) {
        int i4 = t + 256*j;
        int d = i4 >> 4, e0 = (i4 & 15)*4;   // 16 float4 per 64-wide row
        float4 f = ((const float4*)st)[i4];
        float F = fd[d], G = gd[d];
        float4 u = { f.x*F + G*vv[e0],   f.y*F + G*vv[e0+1],
                     f.z*F + G*vv[e0+2], f.w*F + G*vv[e0+3] };
        ((float4*)So)[i4] = u;
    }
}

// ---------------- K4a: head-grouped output-projection GEMM -> contrib buffer -----
// Per block: (head h, 64-row tile, 64-wide m tile). A = top_p-scaled ob rows,
// B = contiguous Wo[h] slab. K-major LDS as in k_proj. Each code appears exactly
// once across all row lists, so plain float4 stores into contrib[code][m].
__global__ __launch_bounds__(256) void k_mergemm(
    const float* __restrict__ Wo,
    const int* __restrict__ cnt, const int* __restrict__ rows,
    const float* __restrict__ topp, const float* __restrict__ ob,
    float* __restrict__ contrib)
{
    int h = blockIdx.x, rt = blockIdx.y, mt = blockIdx.z;
    int n = cnt[h];
    int r0 = rt*64;
    if (r0 >= n) return;
    int nr = min(64, n - r0);

    __shared__ float As[64*LP];   // k-major over e: As[e*LP + r]
    __shared__ float Bs[64*LP];   // k-major over e: Bs[e*LP + m]
    __shared__ int   codes[64];
    __shared__ float scl[64];
    int t = threadIdx.x;
    if (t < 64) {
        int c = rows[h*NB + r0 + min(t, nr-1)];
        codes[t] = c;
        scl[t] = topp[c];
    }
    __syncthreads();

    int lr = t >> 2, e0 = (t & 3)*16;
    {
        const float* srcA = ob + (size_t)codes[lr]*DH + e0;
        float sc = scl[lr];
        const float* srcB = Wo + (size_t)h*DM*DH + (size_t)(mt*64 + lr)*DH + e0;
        #pragma unroll
        for (int j = 0; j < 4; j++) {
            float4 fa = ((const float4*)srcA)[j];
            float4 fb = ((const float4*)srcB)[j];
            int ee = e0 + j*4;
            As[(ee+0)*LP + lr] = fa.x*sc; As[(ee+1)*LP + lr] = fa.y*sc;
            As[(ee+2)*LP + lr] = fa.z*sc; As[(ee+3)*LP + lr] = fa.w*sc;
            Bs[(ee+0)*LP + lr] = fb.x;    Bs[(ee+1)*LP + lr] = fb.y;
            Bs[(ee+2)*LP + lr] = fb.z;    Bs[(ee+3)*LP + lr] = fb.w;
        }
    }
    __syncthreads();

    int tx = t & 15, ty = t >> 4;
    float acc[4][4] = {};
    #pragma unroll 8
    for (int k = 0; k < 64; k++) {
        float4 a4 = *(const float4*)(As + k*LP + ty*4);
        float4 b4 = *(const float4*)(Bs + k*LP + tx*4);
        float a0[4] = {a4.x, a4.y, a4.z, a4.w};
        float b0[4] = {b4.x, b4.y, b4.z, b4.w};
        #pragma unroll
        for (int i=0;i<4;i++)
            #pragma unroll
            for (int j=0;j<4;j++) acc[i][j] += a0[i]*b0[j];
    }

    int mbase = mt*64 + tx*4;
    #pragma unroll
    for (int i = 0; i < 4; i++) {
        int r = ty*4 + i;
        if (r < nr) {
            float4 u = { acc[i][0], acc[i][1], acc[i][2], acc[i][3] };
            *(float4*)(contrib + (size_t)codes[r]*DM + mbase) = u;
        }
    }
}

// ---------------- K4b: finalize merged = sum_a contrib[b,a,:] + top_p*bo ---------
__global__ __launch_bounds__(256) void k_finalize(
    const int* __restrict__ topi, const float* __restrict__ topp,
    const float* __restrict__ bo, const float* __restrict__ contrib,
    float* __restrict__ merged)
{
    int b = blockIdx.x, t = threadIdx.x;
    __shared__ float tp[NA];
    __shared__ int   hh[NA];
    if (t < NA) { tp[t] = topp[b*NA+t]; hh[t] = topi[b*NA+t]; }
    __syncthreads();
    float ax = 0.f, ay = 0.f, az = 0.f, aw = 0.f;
    #pragma unroll
    for (int a = 0; a < NA; a++) {
        float4 cv = ((const float4*)(contrib + (size_t)(b*NA + a)*DM))[t];
        float4 w  = ((const float4*)(bo + (size_t)hh[a]*DM))[t];
        float p = tp[a];
        ax += cv.x + p*w.x; ay += cv.y + p*w.y;
        az += cv.z + p*w.z; aw += cv.w + p*w.w;
    }
    float4 u = { ax, ay, az, aw };
    ((float4*)merged)[(size_t)b*(DM/4) + t] = u;
}

extern "C" void kernel_launch(void* const* d_in, const int* in_sizes, int n_in,
                              void* d_out, int out_size, void* d_ws, size_t ws_size,
                              hipStream_t stream)
{
    const float* query  = (const float*)d_in[0];
    const float* key    = (const float*)d_in[1];
    const float* value  = (const float*)d_in[2];
    const float* matrix = (const float*)d_in[3];
    const float* normal = (const float*)d_in[4];
    const float* Wq = (const float*)d_in[5];
    const float* bq = (const float*)d_in[6];
    const float* Wk = (const float*)d_in[7];
    const float* bk = (const float*)d_in[8];
    const float* Wv = (const float*)d_in[9];
    const float* bv = (const float*)d_in[10];
    const float* Wo = (const float*)d_in[11];
    const float* bo = (const float*)d_in[12];
    const float* We = (const float*)d_in[13];
    const float* be = (const float*)d_in[14];
    const float* Ww = (const float*)d_in[15];
    const float* bw = (const float*)d_in[16];
    const float* dlog = (const float*)d_in[17];

    float* ws = (float*)d_ws;
    int*   cnt  = (int*)ws;                  // 16 ints
    int*   topi = (int*)(ws + 16);           // 4096
    float* topp = ws + 16 + 4096;            // 4096
    float* topl = topp + 4096;               // 4096
    int*   slot = (int*)(topl + 4096);       // 16384
    int*   rows = slot + 16384;              // 16384
    float* qb = (float*)(rows + 16384);      // 262144
    float* kb = qb + 262144;
    float* vb = kb + 262144;
    float* ob = vb + 262144;
    float* contrib = ob + 262144;            // NB*NA*DM = 4M floats (16 MB)

    float* out_merged = (float*)d_out;
    float* out_matrix = out_merged + (size_t)NB*DM;
    float* out_norm   = out_matrix + (size_t)NB*NH*DH*DH;

    hipMemsetAsync(cnt, 0, 16*sizeof(int), stream);
    k_route<<<NB, 256, 0, stream>>>(query, We, be, cnt, topi, topp, topl, slot, rows);
    k_proj<<<dim3(NH, NB/64, 3), 256, 0, stream>>>(query, key, value, Wq, Wk, Wv,
                                                   bq, bk, bv, cnt, rows, qb, kb, vb);
    k_update<<<NB*NH, 256, 0, stream>>>(matrix, normal, Ww, bw, dlog, slot, topl,
                                        qb, kb, vb, ob, out_matrix, out_norm);
    k_mergemm<<<dim3(NH, NB/64, DM/64), 256, 0, stream>>>(Wo, cnt, rows, topp, ob,
                                                          contrib);
    k_finalize<<<NB, 256, 0, stream>>>(topi, topp, bo, contrib, out_merged);
}

// Round 4
// 572.832 us; speedup vs baseline: 1.5728x; 1.0977x over previous
//
#include <hip/hip_runtime.h>
#include <hip/hip_bf16.h>

#define NB 1024
#define DM 1024
#define DH 64
#define NH 16
#define NA 4
#define FEPS 1e-6f

typedef __attribute__((ext_vector_type(8))) short s16x8;   // 8 bf16 (4 VGPRs)
typedef __attribute__((ext_vector_type(4))) float f32x4;   // MFMA accumulator

// round-to-nearest-even f32 -> bf16
__device__ __forceinline__ unsigned short f2bf(float f) {
    unsigned u = __builtin_bit_cast(unsigned, f);
    u += 0x7FFFu + ((u >> 16) & 1u);
    return (unsigned short)(u >> 16);
}
__device__ __forceinline__ unsigned pk2(float x, float y) {
    return (unsigned)f2bf(x) | ((unsigned)f2bf(y) << 16);
}

// ---------------- K1: routing (logits, softmax, top-4, head lists) ----------------
__global__ __launch_bounds__(256) void k_route(
    const float* __restrict__ query,
    const float* __restrict__ We,
    const float* __restrict__ be,
    int* __restrict__ cnt,
    int* __restrict__ topi,
    float* __restrict__ topp,
    float* __restrict__ topl,
    int* __restrict__ slot,
    int* __restrict__ rows)
{
    int b = blockIdx.x, t = threadIdx.x;
    __shared__ float qs[DM];
    __shared__ float lg[NH];
    __shared__ int   sti[NA];
    __shared__ float stp[NA], stl[NA];
    ((float4*)qs)[t] = ((const float4*)(query + (size_t)b*DM))[t];
    __syncthreads();
    // 16 heads x 16 threads each
    int h = t >> 4, l = t & 15;
    const float* w = We + h*DM;
    float p = 0.f;
    for (int j = l; j < DM; j += 16) p += qs[j]*w[j];
    #pragma unroll
    for (int d = 8; d > 0; d >>= 1) p += __shfl_down(p, d, 16);
    if (l == 0) lg[h] = p + be[h];
    __syncthreads();
    if (t == 0) {
        float mx = lg[0];
        for (int i = 1; i < NH; i++) mx = fmaxf(mx, lg[i]);
        float s = 0.f, e[NH];
        for (int i = 0; i < NH; i++) { e[i] = expf(lg[i]-mx); s += e[i]; }
        float inv = 1.f/s;
        unsigned used = 0;
        for (int a = 0; a < NA; a++) {
            int bi = -1; float bv = -1e30f;
            for (int i = 0; i < NH; i++)
                if (!((used>>i)&1u) && lg[i] > bv) { bv = lg[i]; bi = i; }
            used |= 1u << bi;
            sti[a] = bi; stp[a] = e[bi]*inv; stl[a] = lg[bi];
        }
    }
    __syncthreads();
    if (t < NA) {
        int hh = sti[t];
        topi[b*NA+t] = hh; topp[b*NA+t] = stp[t]; topl[b*NA+t] = stl[t];
        int pos = atomicAdd(&cnt[hh], 1);
        rows[hh*NB + pos] = b*NA + t;   // code = b*4 + slot
    }
    if (t < NH) {
        int sl = -1;
        #pragma unroll
        for (int a = 0; a < NA; a++) if (sti[a] == t) sl = a;
        slot[b*NH + t] = sl;
    }
}

// ---------------- K2: gathered per-head projection GEMM via bf16 MFMA -------------
// 64 gathered rows x 64 out-dims, K=1024 in 64-wide tiles. 4 waves; wave w owns
// rows [16w,16w+16). LDS holds A and W tiles in FRAG ORDER: slot
// [(grp*2+s)*64 + lane]*8 bf16, so every fragment read is a contiguous,
// conflict-free wave-wide ds_read_b128.
__global__ __launch_bounds__(256) void k_proj(
    const float* __restrict__ Xq, const float* __restrict__ Xk, const float* __restrict__ Xv,
    const float* __restrict__ Wq, const float* __restrict__ Wk, const float* __restrict__ Wv,
    const float* __restrict__ bq, const float* __restrict__ bk, const float* __restrict__ bv,
    const int* __restrict__ cnt, const int* __restrict__ rows,
    float* __restrict__ qb, float* __restrict__ kb, float* __restrict__ vb)
{
    int h = blockIdx.x, c = blockIdx.y, pz = blockIdx.z;
    int n = cnt[h];
    int r0 = c*64;
    if (r0 >= n) return;
    int nr = min(64, n - r0);
    const float* X    = pz==0 ? Xq : (pz==1 ? Xk : Xv);
    const float* W    = (pz==0 ? Wq : (pz==1 ? Wk : Wv)) + (size_t)h*DH*DM;
    const float* bias = (pz==0 ? bq : (pz==1 ? bk : bv)) + h*DH;
    float* outp = pz==0 ? qb : (pz==1 ? kb : vb);

    __shared__ __align__(16) unsigned short Af[4*2*64*8];  // 8 KB frag-ordered
    __shared__ __align__(16) unsigned short Bf[4*2*64*8];  // 8 KB frag-ordered
    __shared__ int codes[64];
    int t = threadIdx.x;
    if (t < 64) codes[t] = rows[h*NB + r0 + min(t, nr-1)];
    __syncthreads();

    int lane = t & 63, wv = t >> 6;
    int lr = t >> 2;            // staging row (A) / staging m (W), 0..63
    int ks = (t & 3) * 16;      // 16-k segment within the 64-k tile
    int sA = ks >> 5;           // which 32-k half
    int g0 = (ks >> 3) & 3;     // frag k-group of first 8 elems
    int grp = lr >> 4;          // wr for A / mt for W (same formula)
    int dst0 = ((grp*2 + sA)*64 + (lr & 15) + g0*16) * 8;       // ushort units
    int dst1 = ((grp*2 + sA)*64 + (lr & 15) + (g0+1)*16) * 8;
    const float* srcA = X + (size_t)(codes[lr] >> 2)*DM + ks;
    const float* srcB = W + (size_t)lr*DM + ks;

    f32x4 acc[4] = {};   // acc[mt]
    for (int kt = 0; kt < DM; kt += 64) {
        float4 a0 = ((const float4*)(srcA + kt))[0];
        float4 a1 = ((const float4*)(srcA + kt))[1];
        float4 a2 = ((const float4*)(srcA + kt))[2];
        float4 a3 = ((const float4*)(srcA + kt))[3];
        float4 b0 = ((const float4*)(srcB + kt))[0];
        float4 b1 = ((const float4*)(srcB + kt))[1];
        float4 b2 = ((const float4*)(srcB + kt))[2];
        float4 b3 = ((const float4*)(srcB + kt))[3];
        uint4 pA0 = { pk2(a0.x,a0.y), pk2(a0.z,a0.w), pk2(a1.x,a1.y), pk2(a1.z,a1.w) };
        uint4 pA1 = { pk2(a2.x,a2.y), pk2(a2.z,a2.w), pk2(a3.x,a3.y), pk2(a3.z,a3.w) };
        uint4 pB0 = { pk2(b0.x,b0.y), pk2(b0.z,b0.w), pk2(b1.x,b1.y), pk2(b1.z,b1.w) };
        uint4 pB1 = { pk2(b2.x,b2.y), pk2(b2.z,b2.w), pk2(b3.x,b3.y), pk2(b3.z,b3.w) };
        *(uint4*)(Af + dst0) = pA0;
        *(uint4*)(Af + dst1) = pA1;
        *(uint4*)(Bf + dst0) = pB0;
        *(uint4*)(Bf + dst1) = pB1;
        __syncthreads();
        #pragma unroll
        for (int s = 0; s < 2; s++) {
            s16x8 av = *(const s16x8*)(Af + ((wv*2 + s)*64 + lane)*8);
            #pragma unroll
            for (int mt = 0; mt < 4; mt++) {
                s16x8 bv = *(const s16x8*)(Bf + ((mt*2 + s)*64 + lane)*8);
                acc[mt] = __builtin_amdgcn_mfma_f32_16x16x32_bf16(av, bv, acc[mt], 0, 0, 0);
            }
        }
        __syncthreads();
    }

    // C/D layout: col = lane&15, row = (lane>>4)*4 + reg  (within wave's 16-row tile)
    int rbase = wv*16 + (lane >> 4)*4;
    #pragma unroll
    for (int reg = 0; reg < 4; reg++) {
        int r = rbase + reg;
        if (r < nr) {
            int code = codes[r];
            float* dst = outp + (size_t)code*DH;
            #pragma unroll
            for (int mt = 0; mt < 4; mt++) {
                int m = mt*16 + (lane & 15);
                dst[m] = acc[mt][reg] + bias[m];
            }
        }
    }
}

// ---------------- K3: per-(b,h) state copy or linear-attention update -------------
__global__ __launch_bounds__(256) void k_update(
    const float* __restrict__ matrix,
    const float* __restrict__ normalizer,
    const float* __restrict__ Ww, const float* __restrict__ bw,
    const float* __restrict__ dlog,
    const int* __restrict__ slot, const float* __restrict__ topl,
    const float* __restrict__ qb, const float* __restrict__ kb,
    const float* __restrict__ vb, float* __restrict__ ob,
    float* __restrict__ om, float* __restrict__ on)
{
    int bh = blockIdx.x, t = threadIdx.x;
    const float* S = matrix + (size_t)bh*(DH*DH);
    float* So = om + (size_t)bh*(DH*DH);
    int sl = slot[bh];
    if (sl < 0) {
        // pure copy path (12/16 of all blocks): f32 -> f32
        #pragma unroll
        for (int j = 0; j < 4; j++) {
            int i4 = t + 256*j;
            ((float4*)So)[i4] = ((const float4*)S)[i4];
        }
        if (t < DH)
            on[(size_t)bh*DH + t] = normalizer[(size_t)bh*DH + t];
        return;
    }
    int b = bh >> 4, h = bh & 15;
    int code = b*NA + sl;
    __shared__ float st[DH*DH];
    __shared__ float pq[DH], pk[DH], vv[DH], qv[DH], Zs[DH];
    __shared__ float part[256];
    __shared__ float fd[DH], gd[DH];
    __shared__ float scal[4];
    if (t < DH) {
        float qq = qb[code*DH + t]; qv[t] = qq;
        float kk = kb[code*DH + t];
        pq[t] = qq > 0.f ? qq + 1.f : expf(qq);   // elu+1
        pk[t] = kk > 0.f ? kk + 1.f : expf(kk);
        vv[t] = vb[code*DH + t];
        Zs[t] = normalizer[(size_t)bh*DH + t];
    }
    #pragma unroll
    for (int j = 0; j < 4; j++)
        ((float4*)st)[t + 256*j] = ((const float4*)S)[t + 256*j];
    __syncthreads();
    // partial column sums of phi_q^T S : 4 d-groups x 64 columns
    {
        int e = t & 63, dg = t >> 6;
        float s = 0.f;
        #pragma unroll
        for (int d = 0; d < 16; d++) s += pq[dg*16 + d] * st[(dg*16+d)*DH + e];
        part[t] = s;
    }
    if (t < 64) {   // wave 0: scalar reductions
        float r1 = pq[t]*pk[t];            // phi_q . phi_k
        float r2 = pq[t]*(Zs[t]+pk[t]);    // phi_q . Z_new
        #pragma unroll
        for (int d = 32; d > 0; d >>= 1) {
            r1 += __shfl_down(r1, d, 64);
            r2 += __shfl_down(r2, d, 64);
        }
        if (t == 0) { scal[0] = r1; scal[1] = r2 + FEPS; }
    }
    __syncthreads();
    float pqk = scal[0], den = scal[1];
    if (t < 64) {
        float cs = part[t] + part[64+t] + part[128+t] + part[192+t];
        float o = (cs + pqk*vv[t]) / den;
        ob[code*DH + t] = o;
        float r3 = (o + qv[t]) * Ww[h*DH + t];
        #pragma unroll
        for (int d = 32; d > 0; d >>= 1) r3 += __shfl_down(r3, d, 64);
        if (t == 0) {
            float wl = topl[code] + r3 + bw[h];
            scal[2] = 1.f/(1.f + expf(-wl));   // wp
        }
    }
    __syncthreads();
    float wp = scal[2];
    if (t < 64) {
        float dec = 1.f/(1.f + expf(-dlog[h*DH + t]));
        float f1 = 1.f - wp*dec;
        fd[t] = f1;
        gd[t] = wp*pk[t];
        on[(size_t)bh*DH + t] = Zs[t]*f1 + wp*pk[t];
    }
    __syncthreads();
    #pragma unroll
    for (int j = 0; j < 4; j++) {
        int i4 = t + 256*j;
        int d = i4 >> 4, e0 = (i4 & 15)*4;   // 16 float4 per 64-wide row
        float4 f = ((const float4*)st)[i4];
        float F = fd[d], G = gd[d];
        float4 u = { f.x*F + G*vv[e0],   f.y*F + G*vv[e0+1],
                     f.z*F + G*vv[e0+2], f.w*F + G*vv[e0+3] };
        ((float4*)So)[i4] = u;
    }
}

// ---------------- K4a: head-grouped output-projection GEMM via bf16 MFMA ----------
// Per block: (head h, 64-row tile, 64-wide m tile). A = top_p-scaled ob rows,
// B = Wo[h] rows; K = DH = 64 (2 MFMA k-steps). Frag-ordered LDS as in k_proj.
// Each code appears exactly once across all row lists -> plain stores to contrib.
__global__ __launch_bounds__(256) void k_mergemm(
    const float* __restrict__ Wo,
    const int* __restrict__ cnt, const int* __restrict__ rows,
    const float* __restrict__ topp, const float* __restrict__ ob,
    float* __restrict__ contrib)
{
    int h = blockIdx.x, rt = blockIdx.y, mtile = blockIdx.z;
    int n = cnt[h];
    int r0 = rt*64;
    if (r0 >= n) return;
    int nr = min(64, n - r0);

    __shared__ __align__(16) unsigned short Af[4*2*64*8];
    __shared__ __align__(16) unsigned short Bf[4*2*64*8];
    __shared__ int codes[64];
    int t = threadIdx.x;
    if (t < 64) codes[t] = rows[h*NB + r0 + min(t, nr-1)];
    __syncthreads();

    int lane = t & 63, wv = t >> 6;
    int lr = t >> 2;
    int es = (t & 3) * 16;
    int sA = es >> 5;
    int g0 = (es >> 3) & 3;
    int grp = lr >> 4;
    int dst0 = ((grp*2 + sA)*64 + (lr & 15) + g0*16) * 8;
    int dst1 = ((grp*2 + sA)*64 + (lr & 15) + (g0+1)*16) * 8;

    {
        int codeA = codes[lr];
        float sc = topp[codeA];
        const float* srcA = ob + (size_t)codeA*DH + es;
        const float* srcB = Wo + (size_t)h*DM*DH + (size_t)(mtile*64 + lr)*DH + es;
        float4 a0 = ((const float4*)srcA)[0];
        float4 a1 = ((const float4*)srcA)[1];
        float4 a2 = ((const float4*)srcA)[2];
        float4 a3 = ((const float4*)srcA)[3];
        float4 b0 = ((const float4*)srcB)[0];
        float4 b1 = ((const float4*)srcB)[1];
        float4 b2 = ((const float4*)srcB)[2];
        float4 b3 = ((const float4*)srcB)[3];
        uint4 pA0 = { pk2(a0.x*sc,a0.y*sc), pk2(a0.z*sc,a0.w*sc),
                      pk2(a1.x*sc,a1.y*sc), pk2(a1.z*sc,a1.w*sc) };
        uint4 pA1 = { pk2(a2.x*sc,a2.y*sc), pk2(a2.z*sc,a2.w*sc),
                      pk2(a3.x*sc,a3.y*sc), pk2(a3.z*sc,a3.w*sc) };
        uint4 pB0 = { pk2(b0.x,b0.y), pk2(b0.z,b0.w), pk2(b1.x,b1.y), pk2(b1.z,b1.w) };
        uint4 pB1 = { pk2(b2.x,b2.y), pk2(b2.z,b2.w), pk2(b3.x,b3.y), pk2(b3.z,b3.w) };
        *(uint4*)(Af + dst0) = pA0;
        *(uint4*)(Af + dst1) = pA1;
        *(uint4*)(Bf + dst0) = pB0;
        *(uint4*)(Bf + dst1) = pB1;
    }
    __syncthreads();

    f32x4 acc[4] = {};
    #pragma unroll
    for (int s = 0; s < 2; s++) {
        s16x8 av = *(const s16x8*)(Af + ((wv*2 + s)*64 + lane)*8);
        #pragma unroll
        for (int mt = 0; mt < 4; mt++) {
            s16x8 bv = *(const s16x8*)(Bf + ((mt*2 + s)*64 + lane)*8);
            acc[mt] = __builtin_amdgcn_mfma_f32_16x16x32_bf16(av, bv, acc[mt], 0, 0, 0);
        }
    }

    int rbase = wv*16 + (lane >> 4)*4;
    int mbase = mtile*64 + (lane & 15);
    #pragma unroll
    for (int reg = 0; reg < 4; reg++) {
        int r = rbase + reg;
        if (r < nr) {
            float* dst = contrib + (size_t)codes[r]*DM + mbase;
            #pragma unroll
            for (int mt = 0; mt < 4; mt++)
                dst[mt*16] = acc[mt][reg];
        }
    }
}

// ---------------- K4b: finalize merged = sum_a contrib[b,a,:] + top_p*bo ---------
__global__ __launch_bounds__(256) void k_finalize(
    const int* __restrict__ topi, const float* __restrict__ topp,
    const float* __restrict__ bo, const float* __restrict__ contrib,
    float* __restrict__ merged)
{
    int b = blockIdx.x, t = threadIdx.x;
    __shared__ float tp[NA];
    __shared__ int   hh[NA];
    if (t < NA) { tp[t] = topp[b*NA+t]; hh[t] = topi[b*NA+t]; }
    __syncthreads();
    float ax = 0.f, ay = 0.f, az = 0.f, aw = 0.f;
    #pragma unroll
    for (int a = 0; a < NA; a++) {
        float4 cv = ((const float4*)(contrib + (size_t)(b*NA + a)*DM))[t];
        float4 w  = ((const float4*)(bo + (size_t)hh[a]*DM))[t];
        float p = tp[a];
        ax += cv.x + p*w.x; ay += cv.y + p*w.y;
        az += cv.z + p*w.z; aw += cv.w + p*w.w;
    }
    float4 u = { ax, ay, az, aw };
    ((float4*)merged)[(size_t)b*(DM/4) + t] = u;
}

extern "C" void kernel_launch(void* const* d_in, const int* in_sizes, int n_in,
                              void* d_out, int out_size, void* d_ws, size_t ws_size,
                              hipStream_t stream)
{
    const float* query  = (const float*)d_in[0];
    const float* key    = (const float*)d_in[1];
    const float* value  = (const float*)d_in[2];
    const float* matrix = (const float*)d_in[3];
    const float* normal = (const float*)d_in[4];
    const float* Wq = (const float*)d_in[5];
    const float* bq = (const float*)d_in[6];
    const float* Wk = (const float*)d_in[7];
    const float* bk = (const float*)d_in[8];
    const float* Wv = (const float*)d_in[9];
    const float* bv = (const float*)d_in[10];
    const float* Wo = (const float*)d_in[11];
    const float* bo = (const float*)d_in[12];
    const float* We = (const float*)d_in[13];
    const float* be = (const float*)d_in[14];
    const float* Ww = (const float*)d_in[15];
    const float* bw = (const float*)d_in[16];
    const float* dlog = (const float*)d_in[17];

    float* ws = (float*)d_ws;
    int*   cnt  = (int*)ws;                  // 16 ints
    int*   topi = (int*)(ws + 16);           // 4096
    float* topp = ws + 16 + 4096;            // 4096
    float* topl = topp + 4096;               // 4096
    int*   slot = (int*)(topl + 4096);       // 16384
    int*   rows = slot + 16384;              // 16384
    float* qb = (float*)(rows + 16384);      // 262144
    float* kb = qb + 262144;
    float* vb = kb + 262144;
    float* ob = vb + 262144;
    float* contrib = ob + 262144;            // NB*NA*DM = 4M floats (16 MB)

    float* out_merged = (float*)d_out;
    float* out_matrix = out_merged + (size_t)NB*DM;
    float* out_norm   = out_matrix + (size_t)NB*NH*DH*DH;

    hipMemsetAsync(cnt, 0, 16*sizeof(int), stream);
    k_route<<<NB, 256, 0, stream>>>(query, We, be, cnt, topi, topp, topl, slot, rows);
    k_proj<<<dim3(NH, NB/64, 3), 256, 0, stream>>>(query, key, value, Wq, Wk, Wv,
                                                   bq, bk, bv, cnt, rows, qb, kb, vb);
    k_update<<<NB*NH, 256, 0, stream>>>(matrix, normal, Ww, bw, dlog, slot, topl,
                                        qb, kb, vb, ob, out_matrix, out_norm);
    k_mergemm<<<dim3(NH, NB/64, DM/64), 256, 0, stream>>>(Wo, cnt, rows, topp, ob,
                                                          contrib);
    k_finalize<<<NB, 256, 0, stream>>>(topi, topp, bo, contrib, out_merged);
}